// Round 15
// baseline (446.019 us; speedup 1.0000x reference)
//
#include <hip/hip_runtime.h>
#include <hip/hip_bf16.h>

#define B_ 8
#define T_ 2048
#define D_ 256
#define S_ 2048
#define NBLK2 1792              // 7 blocks/CU x 256 CU -> all co-resident (LDS 16.5KB, 28 waves/CU)
#define NW (NBLK2 * 4)          // 7168 waves in k_bpool

// Kernel 1: cos[b,t] = <f[t],f[t+1]> / max(|f[t]||f[t+1]|, 1e-6), t in [0,T-2].
// One wave per row t (4096 blocks -> max TLP). Block 0 also zeroes the 8 batch
// flags used by k_bpool (visible at kernel end; re-zeroed every call/replay).
__global__ __launch_bounds__(256) void k_dotcos(const float* __restrict__ fr,
                                                float* __restrict__ cosg,
                                                int* __restrict__ flags){
  if (blockIdx.x == 0 && threadIdx.x < B_) flags[threadIdx.x] = 0;
  int lane = threadIdx.x & 63;
  int w = threadIdx.x >> 6;
  int p = blockIdx.x * 4 + w;                 // p = b*T + t
  int t = p & (T_ - 1);
  const float4* f4 = (const float4*)fr;
  float4 a = f4[(size_t)p * 64 + lane];
  float na = a.x*a.x + a.y*a.y + a.z*a.z + a.w*a.w;
  float nc = 0.0f, dt = 0.0f;
  if (t < T_ - 1){
    float4 c = f4[(size_t)(p + 1) * 64 + lane];
    nc = c.x*c.x + c.y*c.y + c.z*c.z + c.w*c.w;
    dt = a.x*c.x + a.y*c.y + a.z*c.z + a.w*c.w;
  }
  #pragma unroll
  for (int m = 32; m >= 1; m >>= 1){
    na += __shfl_xor(na, m, 64);
    nc += __shfl_xor(nc, m, 64);
    dt += __shfl_xor(dt, m, 64);
  }
  if (lane == 0 && t < T_ - 1)
    cosg[p] = dt / fmaxf(sqrtf(na) * sqrtf(nc), 1e-6f);
}

// Kernel 2 (boundary + pool, flag-synced):
//  - blocks 0..7: boundary chain for batch blk (bit-identical to r14), write
//    bcg/numfrg/lotbl, __threadfence, release-store flags[blk]=1. Then pool.
//  - all blocks: pool pairs (reversed grid-stride over 16384 (b,s)); each pair
//    acquire-spins on flags[b] (cheap; producers never wait first -> no cycle;
//    grid <= co-resident capacity -> producers always scheduled).
__global__ __launch_bounds__(256, 7) void k_bpool(const float* __restrict__ fr,
                                                  const float* __restrict__ cosg,
                                                  float* __restrict__ bcg,
                                                  float* __restrict__ numfrg,
                                                  int* __restrict__ lotbl,
                                                  int* __restrict__ flags,
                                                  float* __restrict__ out){
  __shared__ float sd[T_];
  __shared__ float sb[T_];
  __shared__ float smin[4], smax[4], swv[4], snum;
  int tid = threadIdx.x;
  int lane = tid & 63, w = tid >> 6;
  int blk = blockIdx.x;

  if (blk < B_){
    int b = blk;
    const float* cG = cosg + b * T_;
    for (int t = tid; t < T_ - 1; t += 256) sd[t] = cG[t];
    __syncthreads();
    float mn = 1e30f, mx = -1e30f;
    for (int t = tid; t < T_ - 1; t += 256){ float v = sd[t]; mn = fminf(mn, v); mx = fmaxf(mx, v); }
    #pragma unroll
    for (int m = 32; m >= 1; m >>= 1){
      mn = fminf(mn, __shfl_xor(mn, m, 64));
      mx = fmaxf(mx, __shfl_xor(mx, m, 64));
    }
    if (lane == 0){ smin[w] = mn; smax[w] = mx; }
    __syncthreads();
    mn = fminf(fminf(smin[0], smin[1]), fminf(smin[2], smin[3]));
    mx = fmaxf(fmaxf(smax[0], smax[1]), fmaxf(smax[2], smax[3]));
    float inv = 1.0f / (mx - mn);
    for (int t = tid; t < T_ - 1; t += 256)
      sd[t] = 1.0f - (sd[t] - mn) * inv;
    __syncthreads();
    for (int t = tid; t < T_; t += 256){
      float v;
      if (t == 0) v = 1.0f;
      else {
        int i = t - 1;                          // index into d (length T-1)
        if (i < 2 || i > T_ - 4) v = 0.0f;      // p2[:, :2] = 0, p2[:, -2:] = 0
        else {
          float d0 = sd[i];
          float p2 = fminf(fmaxf(d0 - sd[i + 2], 0.0f), fmaxf(d0 - sd[i - 2], 0.0f));
          v = tanhf(1e7f * p2);
        }
      }
      sb[t] = v;
    }
    __syncthreads();
    float loc[8]; float s = 0.0f;
    #pragma unroll
    for (int j = 0; j < 8; ++j){ s += sb[8 * tid + j]; loc[j] = s; }
    float v = s;
    #pragma unroll
    for (int off = 1; off < 64; off <<= 1){
      float n = __shfl_up(v, (unsigned)off, 64);
      if (lane >= off) v += n;
    }
    if (lane == 63) swv[w] = v;
    __syncthreads();
    float wpre = 0.0f;
    for (int i = 0; i < w; ++i) wpre += swv[i];
    float excl = wpre + v - s;
    #pragma unroll
    for (int j = 0; j < 8; ++j){
      float bcv = excl + loc[j];
      sd[8 * tid + j] = bcv;
      bcg[b * T_ + 8 * tid + j] = bcv;
    }
    if (tid == 255){ numfrg[b] = excl + s; snum = excl + s; }
    __syncthreads();
    float nf = snum;
    for (int si = tid; si < S_; si += 256){
      int lo = T_;
      float cc = (float)(si + 1);
      if (cc <= nf){
        float lov = cc - 1.0f;
        lo = 0; int hi = T_;
        while (lo < hi){ int mid = (lo + hi) >> 1; if (sd[mid] < lov) lo = mid + 1; else hi = mid; }
      }
      lotbl[b * S_ + si] = lo;
    }
    __syncthreads();
    if (tid == 0){
      __threadfence();
      __hip_atomic_store(&flags[b], 1, __ATOMIC_RELEASE, __HIP_MEMORY_SCOPE_AGENT);
    }
  }

  // ---- pool: reversed grid-stride so blocks 0..7 take the cheap tail ----
  int wg = blk * 4 + w;
  int widx = (NW - 1) - wg;
  for (int idx = widx; idx < B_ * S_; idx += NW){
    int b = idx >> 11;
    int s = idx & (S_ - 1);
    while (__hip_atomic_load(&flags[b], __ATOMIC_ACQUIRE, __HIP_MEMORY_SCOPE_AGENT) == 0)
      __builtin_amdgcn_s_sleep(2);
    float numfr = numfrg[b];
    float4 acc = {0.0f, 0.0f, 0.0f, 0.0f};
    if ((float)(s + 1) <= numfr){
      float cc = (float)(s + 1);
      float hiv = cc + 1.0f;
      int lo = lotbl[b * S_ + s];
      const float* bcb = bcg + b * T_;
      const float4* f4 = (const float4*)(fr + (size_t)b * T_ * D_);
      float scol = 0.0f;
      for (int base = lo; base < T_; base += 64){
        int t = base + lane;
        float bcv = (t < T_) ? bcb[t] : 1e30f;
        bool in = bcv <= hiv;
        float r = in ? 1.0f - tanhf(10.0f * fabsf(cc - bcv)) : 0.0f;
        #pragma unroll
        for (int m = 32; m >= 1; m >>= 1) r += __shfl_xor(r, m, 64);
        scol += r;
        if (__popcll(__ballot(in)) < 64) break;
      }
      for (int base = lo; base < T_; base += 64){
        int t = base + lane;
        float bcv = (t < T_) ? bcb[t] : 1e30f;
        bool in = bcv <= hiv;
        float mval = 0.0f;
        if (in){
          float u = tanhf(10.0f * fabsf(cc - bcv));
          mval = (1.0f - u) / (scol + u);
        }
        int cnt = __popcll(__ballot(in));
        for (int j = 0; j < cnt; ++j){
          float mj = __shfl(mval, j, 64);
          float4 f = f4[(size_t)(base + j) * 64 + lane];
          acc.x += mj * f.x; acc.y += mj * f.y; acc.z += mj * f.z; acc.w += mj * f.w;
        }
        if (cnt < 64) break;
      }
    }
    ((float4*)out)[((size_t)b * S_ + s) * 64 + lane] = acc;
  }
}

extern "C" void kernel_launch(void* const* d_in, const int* in_sizes, int n_in,
                              void* d_out, int out_size, void* d_ws, size_t ws_size,
                              hipStream_t stream) {
  const float* frames = (const float*)d_in[0];
  float* ws = (float*)d_ws;
  float* cosg   = ws;                          // B*T floats
  float* bcg    = ws + B_ * T_;                // B*T floats
  float* numfrg = ws + 2 * B_ * T_;            // B floats
  int*   flags  = (int*)(ws + 2 * B_ * T_ + 16);   // B ints
  int*   lotbl  = (int*)(ws + 2 * B_ * T_ + 32);   // B*S ints
  float* out = (float*)d_out;

  k_dotcos<<<B_ * T_ / 4, 256, 0, stream>>>(frames, cosg, flags);
  k_bpool<<<NBLK2, 256, 0, stream>>>(frames, cosg, bcg, numfrg, lotbl, flags, out);
}

// Round 16
// 36.905 us; speedup vs baseline: 12.0855x; 12.0855x over previous
//
#include <hip/hip_runtime.h>
#include <hip/hip_bf16.h>

#define B_ 8
#define T_ 2048
#define D_ 256
#define S_ 2048

// Kernel 1: cos[b,t] = <f[t],f[t+1]> / max(|f[t]||f[t+1]|, 1e-6), t in [0,T-2].
// One wave per row t (4096 blocks -> max TLP). Verbatim r14 (proven).
__global__ __launch_bounds__(256) void k_dotcos(const float* __restrict__ fr,
                                                float* __restrict__ cosg){
  int lane = threadIdx.x & 63;
  int w = threadIdx.x >> 6;
  int p = blockIdx.x * 4 + w;                 // p = b*T + t
  int t = p & (T_ - 1);
  const float4* f4 = (const float4*)fr;
  float4 a = f4[(size_t)p * 64 + lane];
  float na = a.x*a.x + a.y*a.y + a.z*a.z + a.w*a.w;
  float nc = 0.0f, dt = 0.0f;
  if (t < T_ - 1){
    float4 c = f4[(size_t)(p + 1) * 64 + lane];
    nc = c.x*c.x + c.y*c.y + c.z*c.z + c.w*c.w;
    dt = a.x*c.x + a.y*c.y + a.z*c.z + a.w*c.w;
  }
  #pragma unroll
  for (int m = 32; m >= 1; m >>= 1){
    na += __shfl_xor(na, m, 64);
    nc += __shfl_xor(nc, m, 64);
    dt += __shfl_xor(dt, m, 64);
  }
  if (lane == 0 && t < T_ - 1)
    cosg[p] = dt / fmaxf(sqrtf(na) * sqrtf(nc), 1e-6f);
}

// Kernel 2 (fused): each block (128 s-tiles x 8 batches = 1024 blocks)
// recomputes its batch's boundary chain from cosg — op-order bit-identical
// to r14's k_boundary — leaving bc in LDS (sd), then pools 16 s values
// (4 waves x 4 s serially) with the r14 lane-parallel window body.
// No bcg/lotbl/numfrg globals, no third kernel, no cross-block sync.
__global__ __launch_bounds__(256) void k_fused(const float* __restrict__ fr,
                                               const float* __restrict__ cosg,
                                               float* __restrict__ out){
  __shared__ float sd[T_];     // cos -> d -> (after scan) bc
  __shared__ float sb[T_];     // b values
  __shared__ float smin[4], smax[4], swv[4], snum;
  int tid = threadIdx.x;
  int lane = tid & 63, w = tid >> 6;
  int b = blockIdx.y;
  int s0 = blockIdx.x * 16;

  // ---- boundary preamble (bit-identical to r14 k_boundary) ----
  const float* cG = cosg + b * T_;
  for (int t = tid; t < T_ - 1; t += 256) sd[t] = cG[t];
  __syncthreads();
  float mn = 1e30f, mx = -1e30f;
  for (int t = tid; t < T_ - 1; t += 256){ float v = sd[t]; mn = fminf(mn, v); mx = fmaxf(mx, v); }
  #pragma unroll
  for (int m = 32; m >= 1; m >>= 1){
    mn = fminf(mn, __shfl_xor(mn, m, 64));
    mx = fmaxf(mx, __shfl_xor(mx, m, 64));
  }
  if (lane == 0){ smin[w] = mn; smax[w] = mx; }
  __syncthreads();
  mn = fminf(fminf(smin[0], smin[1]), fminf(smin[2], smin[3]));
  mx = fmaxf(fmaxf(smax[0], smax[1]), fmaxf(smax[2], smax[3]));
  float inv = 1.0f / (mx - mn);
  for (int t = tid; t < T_ - 1; t += 256)
    sd[t] = 1.0f - (sd[t] - mn) * inv;
  __syncthreads();
  for (int t = tid; t < T_; t += 256){
    float v;
    if (t == 0) v = 1.0f;
    else {
      int i = t - 1;                          // index into d (length T-1)
      if (i < 2 || i > T_ - 4) v = 0.0f;      // p2[:, :2] = 0, p2[:, -2:] = 0
      else {
        float d0 = sd[i];
        float p2 = fminf(fmaxf(d0 - sd[i + 2], 0.0f), fmaxf(d0 - sd[i - 2], 0.0f));
        v = tanhf(1e7f * p2);
      }
    }
    sb[t] = v;
  }
  __syncthreads();
  float loc[8]; float ssum = 0.0f;
  #pragma unroll
  for (int j = 0; j < 8; ++j){ ssum += sb[8 * tid + j]; loc[j] = ssum; }
  float v = ssum;
  #pragma unroll
  for (int off = 1; off < 64; off <<= 1){
    float n = __shfl_up(v, (unsigned)off, 64);
    if (lane >= off) v += n;
  }
  if (lane == 63) swv[w] = v;
  __syncthreads();
  float wpre = 0.0f;
  for (int i = 0; i < w; ++i) wpre += swv[i];
  float excl = wpre + v - ssum;
  #pragma unroll
  for (int j = 0; j < 8; ++j) sd[8 * tid + j] = excl + loc[j];   // bc -> LDS
  if (tid == 255) snum = excl + ssum;
  __syncthreads();
  float numfr = snum;

  // ---- pool: 4 s per wave, lane-parallel window (r14 body, bc from LDS) ----
  const float4* f4 = (const float4*)(fr + (size_t)b * T_ * D_);
  if ((float)(s0 + 1) > numfr){
    // all 16 s invalid: ref res underflows to 0 in f32 -> exact zeros.
    float4 z = {0.0f, 0.0f, 0.0f, 0.0f};
    #pragma unroll
    for (int k = 0; k < 4; ++k)
      ((float4*)out)[((size_t)b * S_ + (s0 + w * 4 + k)) * 64 + lane] = z;
    return;
  }
  for (int k = 0; k < 4; ++k){
    int s = s0 + w * 4 + k;
    float4 acc = {0.0f, 0.0f, 0.0f, 0.0f};
    if ((float)(s + 1) <= numfr){
      float cc = (float)(s + 1);
      float lov = cc - 1.0f, hiv = cc + 1.0f;
      int lo = 0, hi = T_;
      while (lo < hi){ int mid = (lo + hi) >> 1; if (sd[mid] < lov) lo = mid + 1; else hi = mid; }
      float scol = 0.0f;
      for (int base = lo; base < T_; base += 64){
        int t = base + lane;
        float bcv = (t < T_) ? sd[t] : 1e30f;
        bool in = bcv <= hiv;
        float r = in ? 1.0f - tanhf(10.0f * fabsf(cc - bcv)) : 0.0f;
        #pragma unroll
        for (int m = 32; m >= 1; m >>= 1) r += __shfl_xor(r, m, 64);
        scol += r;
        if (__popcll(__ballot(in)) < 64) break;
      }
      for (int base = lo; base < T_; base += 64){
        int t = base + lane;
        float bcv = (t < T_) ? sd[t] : 1e30f;
        bool in = bcv <= hiv;
        float mval = 0.0f;
        if (in){
          float u = tanhf(10.0f * fabsf(cc - bcv));
          mval = (1.0f - u) / (scol + u);
        }
        int cnt = __popcll(__ballot(in));
        for (int j = 0; j < cnt; ++j){
          float mj = __shfl(mval, j, 64);
          float4 f = f4[(size_t)(base + j) * 64 + lane];
          acc.x += mj * f.x; acc.y += mj * f.y; acc.z += mj * f.z; acc.w += mj * f.w;
        }
        if (cnt < 64) break;
      }
    }
    ((float4*)out)[((size_t)b * S_ + s) * 64 + lane] = acc;
  }
}

extern "C" void kernel_launch(void* const* d_in, const int* in_sizes, int n_in,
                              void* d_out, int out_size, void* d_ws, size_t ws_size,
                              hipStream_t stream) {
  const float* frames = (const float*)d_in[0];
  float* cosg = (float*)d_ws;            // B*T floats
  float* out = (float*)d_out;

  k_dotcos<<<B_ * T_ / 4, 256, 0, stream>>>(frames, cosg);
  k_fused<<<dim3(S_ / 16, B_), 256, 0, stream>>>(frames, cosg, out);
}

// Round 17
// 25.244 us; speedup vs baseline: 17.6682x; 1.4619x over previous
//
#include <hip/hip_runtime.h>
#include <hip/hip_bf16.h>

#define B_ 8
#define T_ 2048
#define D_ 256
#define S_ 2048

// Kernel 1: cos[b,t] = <f[t],f[t+1]> / max(|f[t]||f[t+1]|, 1e-6), t in [0,T-2].
// One wave per row t. 1-D grid with b = blockIdx&7: under the g%8 XCD
// round-robin each XCD serves ONE batch (2.1MB frames -> L2-resident).
__global__ __launch_bounds__(256) void k_dotcos(const float* __restrict__ fr,
                                                float* __restrict__ cosg){
  int lane = threadIdx.x & 63;
  int w = threadIdx.x >> 6;
  int b = blockIdx.x & 7;
  int chunk = blockIdx.x >> 3;                // 0..511
  int t = chunk * 4 + w;                      // 0..2047
  int p = b * T_ + t;
  const float4* f4 = (const float4*)fr;
  float4 a = f4[(size_t)p * 64 + lane];
  float na = a.x*a.x + a.y*a.y + a.z*a.z + a.w*a.w;
  float nc = 0.0f, dt = 0.0f;
  if (t < T_ - 1){
    float4 c = f4[(size_t)(p + 1) * 64 + lane];
    nc = c.x*c.x + c.y*c.y + c.z*c.z + c.w*c.w;
    dt = a.x*c.x + a.y*c.y + a.z*c.z + a.w*c.w;
  }
  #pragma unroll
  for (int m = 32; m >= 1; m >>= 1){
    na += __shfl_xor(na, m, 64);
    nc += __shfl_xor(nc, m, 64);
    dt += __shfl_xor(dt, m, 64);
  }
  if (lane == 0 && t < T_ - 1)
    cosg[p] = dt / fmaxf(sqrtf(na) * sqrtf(nc), 1e-6f);
}

// Kernel 2: per batch: minmax(cos) -> d -> p2 -> b -> block scan -> bc,
// then per-s window starts lo_tbl. Verbatim r14 (proven, absmax 0.0).
__global__ __launch_bounds__(256) void k_boundary(const float* __restrict__ cosg,
                                                  float* __restrict__ bcg,
                                                  float* __restrict__ numfrg,
                                                  int* __restrict__ lotbl){
  __shared__ float sd[T_];
  __shared__ float sb[T_];
  __shared__ float smin[4], smax[4], swv[4], snum;
  int b = blockIdx.x, tid = threadIdx.x;
  int lane = tid & 63, w = tid >> 6;
  const float* cG = cosg + b * T_;
  for (int t = tid; t < T_ - 1; t += 256) sd[t] = cG[t];
  __syncthreads();
  float mn = 1e30f, mx = -1e30f;
  for (int t = tid; t < T_ - 1; t += 256){ float v = sd[t]; mn = fminf(mn, v); mx = fmaxf(mx, v); }
  #pragma unroll
  for (int m = 32; m >= 1; m >>= 1){
    mn = fminf(mn, __shfl_xor(mn, m, 64));
    mx = fmaxf(mx, __shfl_xor(mx, m, 64));
  }
  if (lane == 0){ smin[w] = mn; smax[w] = mx; }
  __syncthreads();
  mn = fminf(fminf(smin[0], smin[1]), fminf(smin[2], smin[3]));
  mx = fmaxf(fmaxf(smax[0], smax[1]), fmaxf(smax[2], smax[3]));
  float inv = 1.0f / (mx - mn);
  for (int t = tid; t < T_ - 1; t += 256)
    sd[t] = 1.0f - (sd[t] - mn) * inv;
  __syncthreads();
  for (int t = tid; t < T_; t += 256){
    float v;
    if (t == 0) v = 1.0f;
    else {
      int i = t - 1;                          // index into d (length T-1)
      if (i < 2 || i > T_ - 4) v = 0.0f;      // p2[:, :2] = 0, p2[:, -2:] = 0
      else {
        float d0 = sd[i];
        float p2 = fminf(fmaxf(d0 - sd[i + 2], 0.0f), fmaxf(d0 - sd[i - 2], 0.0f));
        v = tanhf(1e7f * p2);
      }
    }
    sb[t] = v;
  }
  __syncthreads();
  float loc[8]; float s = 0.0f;
  #pragma unroll
  for (int j = 0; j < 8; ++j){ s += sb[8 * tid + j]; loc[j] = s; }
  float v = s;
  #pragma unroll
  for (int off = 1; off < 64; off <<= 1){
    float n = __shfl_up(v, (unsigned)off, 64);
    if (lane >= off) v += n;
  }
  if (lane == 63) swv[w] = v;
  __syncthreads();
  float wpre = 0.0f;
  for (int i = 0; i < w; ++i) wpre += swv[i];
  float excl = wpre + v - s;
  #pragma unroll
  for (int j = 0; j < 8; ++j){
    float bcv = excl + loc[j];
    sd[8 * tid + j] = bcv;                    // bc into LDS for the searches
    bcg[b * T_ + 8 * tid + j] = bcv;
  }
  if (tid == 255){ numfrg[b] = excl + s; snum = excl + s; }
  __syncthreads();
  float nf = snum;
  for (int si = tid; si < S_; si += 256){
    int lo = T_;
    float cc = (float)(si + 1);
    if (cc <= nf){
      float lov = cc - 1.0f;
      lo = 0; int hi = T_;
      while (lo < hi){ int mid = (lo + hi) >> 1; if (sd[mid] < lov) lo = mid + 1; else hi = mid; }
    }
    lotbl[b * S_ + si] = lo;
  }
}

// Kernel 3: one WAVE per s, LDS-free (verbatim r14 body). 1-D grid with
// b = blockIdx&7 so each XCD pools ONE batch: window float4 loads hit L2.
__global__ __launch_bounds__(256) void k_pool(const float* __restrict__ fr,
                                              const float* __restrict__ bcg,
                                              const float* __restrict__ numfrg,
                                              const int* __restrict__ lotbl,
                                              float* __restrict__ out){
  int tid = threadIdx.x;
  int lane = tid & 63, w = tid >> 6;
  int b = blockIdx.x & 7;
  int sblk = blockIdx.x >> 3;                 // 0..511
  int s = sblk * 4 + w;
  float numfr = numfrg[b];
  float4 acc = {0.0f, 0.0f, 0.0f, 0.0f};
  if ((float)(sblk * 4 + 1) <= numfr && (float)(s + 1) <= numfr){
    float cc = (float)(s + 1);
    float hiv = cc + 1.0f;
    int lo = lotbl[b * S_ + s];
    const float* bcb = bcg + b * T_;
    const float4* f4 = (const float4*)(fr + (size_t)b * T_ * D_);
    float scol = 0.0f;
    for (int base = lo; base < T_; base += 64){
      int t = base + lane;
      float bcv = (t < T_) ? bcb[t] : 1e30f;
      bool in = bcv <= hiv;
      float r = in ? 1.0f - tanhf(10.0f * fabsf(cc - bcv)) : 0.0f;
      #pragma unroll
      for (int m = 32; m >= 1; m >>= 1) r += __shfl_xor(r, m, 64);
      scol += r;
      if (__popcll(__ballot(in)) < 64) break;
    }
    for (int base = lo; base < T_; base += 64){
      int t = base + lane;
      float bcv = (t < T_) ? bcb[t] : 1e30f;
      bool in = bcv <= hiv;
      float mval = 0.0f;
      if (in){
        float u = tanhf(10.0f * fabsf(cc - bcv));
        mval = (1.0f - u) / (scol + u);
      }
      int cnt = __popcll(__ballot(in));
      for (int j = 0; j < cnt; ++j){
        float mj = __shfl(mval, j, 64);
        float4 f = f4[(size_t)(base + j) * 64 + lane];
        acc.x += mj * f.x; acc.y += mj * f.y; acc.z += mj * f.z; acc.w += mj * f.w;
      }
      if (cnt < 64) break;
    }
  }
  ((float4*)out)[((size_t)b * S_ + s) * 64 + lane] = acc;
}

extern "C" void kernel_launch(void* const* d_in, const int* in_sizes, int n_in,
                              void* d_out, int out_size, void* d_ws, size_t ws_size,
                              hipStream_t stream) {
  const float* frames = (const float*)d_in[0];
  float* ws = (float*)d_ws;
  float* cosg   = ws;                    // B*T
  float* bcg    = ws + B_ * T_;          // B*T
  float* numfrg = ws + 2 * B_ * T_;      // B
  int*   lotbl  = (int*)(ws + 2 * B_ * T_ + 64);   // B*S ints
  float* out = (float*)d_out;

  k_dotcos<<<B_ * T_ / 4, 256, 0, stream>>>(frames, cosg);
  k_boundary<<<B_, 256, 0, stream>>>(cosg, bcg, numfrg, lotbl);
  k_pool<<<B_ * S_ / 4, 256, 0, stream>>>(frames, bcg, numfrg, lotbl, out);
}

// Round 18
// 23.471 us; speedup vs baseline: 19.0032x; 1.0756x over previous
//
#include <hip/hip_runtime.h>
#include <hip/hip_bf16.h>

#define B_ 8
#define T_ 2048
#define D_ 256
#define S_ 2048

// Kernel 1: cos[b,t] = <f[t],f[t+1]> / max(|f[t]||f[t+1]|, 1e-6), t in [0,T-2].
// One wave per row t. 1-D grid with b = blockIdx&7: under the g%8 XCD
// round-robin each XCD serves ONE batch (2.1MB frames -> L2-resident).
__global__ __launch_bounds__(256) void k_dotcos(const float* __restrict__ fr,
                                                float* __restrict__ cosg){
  int lane = threadIdx.x & 63;
  int w = threadIdx.x >> 6;
  int b = blockIdx.x & 7;
  int chunk = blockIdx.x >> 3;                // 0..511
  int t = chunk * 4 + w;                      // 0..2047
  int p = b * T_ + t;
  const float4* f4 = (const float4*)fr;
  float4 a = f4[(size_t)p * 64 + lane];
  float na = a.x*a.x + a.y*a.y + a.z*a.z + a.w*a.w;
  float nc = 0.0f, dt = 0.0f;
  if (t < T_ - 1){
    float4 c = f4[(size_t)(p + 1) * 64 + lane];
    nc = c.x*c.x + c.y*c.y + c.z*c.z + c.w*c.w;
    dt = a.x*c.x + a.y*c.y + a.z*c.z + a.w*c.w;
  }
  #pragma unroll
  for (int m = 32; m >= 1; m >>= 1){
    na += __shfl_xor(na, m, 64);
    nc += __shfl_xor(nc, m, 64);
    dt += __shfl_xor(dt, m, 64);
  }
  if (lane == 0 && t < T_ - 1)
    cosg[p] = dt / fmaxf(sqrtf(na) * sqrtf(nc), 1e-6f);
}

// Kernel 2: per batch: minmax(cos) -> d -> p2 -> b -> block scan -> bc.
// lotbl now computed by EVENT SCATTER instead of per-s binary search:
// b in {0,1} exactly (saturated tanh; proven r1==r2 bit-identical), so bc is
// an integer staircase incrementing by 1; lotbl[k] = t where bc first reaches
// k. Zero-init covers s in {0,1}; any hypothetical fractional-b entry stays 0,
// which is numerically identical (excluded terms have res == 0.0f exactly).
__global__ __launch_bounds__(256) void k_boundary(const float* __restrict__ cosg,
                                                  float* __restrict__ bcg,
                                                  float* __restrict__ numfrg,
                                                  int* __restrict__ lotbl){
  __shared__ float sd[T_];
  __shared__ float sb[T_];
  __shared__ float smin[4], smax[4], swv[4];
  int b = blockIdx.x, tid = threadIdx.x;
  int lane = tid & 63, w = tid >> 6;
  const float* cG = cosg + b * T_;
  for (int t = tid; t < T_ - 1; t += 256) sd[t] = cG[t];
  // zero this batch's lotbl row while waiting (global, ordered by fence+sync below)
  for (int si = tid; si < S_; si += 256) lotbl[b * S_ + si] = 0;
  __syncthreads();
  float mn = 1e30f, mx = -1e30f;
  for (int t = tid; t < T_ - 1; t += 256){ float v = sd[t]; mn = fminf(mn, v); mx = fmaxf(mx, v); }
  #pragma unroll
  for (int m = 32; m >= 1; m >>= 1){
    mn = fminf(mn, __shfl_xor(mn, m, 64));
    mx = fmaxf(mx, __shfl_xor(mx, m, 64));
  }
  if (lane == 0){ smin[w] = mn; smax[w] = mx; }
  __syncthreads();
  mn = fminf(fminf(smin[0], smin[1]), fminf(smin[2], smin[3]));
  mx = fmaxf(fmaxf(smax[0], smax[1]), fmaxf(smax[2], smax[3]));
  float inv = 1.0f / (mx - mn);
  for (int t = tid; t < T_ - 1; t += 256)
    sd[t] = 1.0f - (sd[t] - mn) * inv;
  __syncthreads();
  for (int t = tid; t < T_; t += 256){
    float v;
    if (t == 0) v = 1.0f;
    else {
      int i = t - 1;                          // index into d (length T-1)
      if (i < 2 || i > T_ - 4) v = 0.0f;      // p2[:, :2] = 0, p2[:, -2:] = 0
      else {
        float d0 = sd[i];
        float p2 = fminf(fmaxf(d0 - sd[i + 2], 0.0f), fmaxf(d0 - sd[i - 2], 0.0f));
        v = tanhf(1e7f * p2);
      }
    }
    sb[t] = v;
  }
  __syncthreads();
  float loc[8]; float s = 0.0f;
  #pragma unroll
  for (int j = 0; j < 8; ++j){ s += sb[8 * tid + j]; loc[j] = s; }
  float v = s;
  #pragma unroll
  for (int off = 1; off < 64; off <<= 1){
    float n = __shfl_up(v, (unsigned)off, 64);
    if (lane >= off) v += n;
  }
  if (lane == 63) swv[w] = v;
  __syncthreads();
  float wpre = 0.0f;
  for (int i = 0; i < w; ++i) wpre += swv[i];
  float excl = wpre + v - s;
  #pragma unroll
  for (int j = 0; j < 8; ++j) bcg[b * T_ + 8 * tid + j] = excl + loc[j];
  if (tid == 255) numfrg[b] = excl + s;
  // order the zero-stores before the scatter stores (same block, same L1/L2)
  __threadfence_block();
  __syncthreads();
  #pragma unroll
  for (int j = 0; j < 8; ++j){
    if (sb[8 * tid + j] == 1.0f){
      int k = (int)(excl + loc[j]);           // bc[t], an exact integer
      if (k < S_) lotbl[b * S_ + k] = 8 * tid + j;
    }
  }
}

// Kernel 3: one WAVE per s, LDS-free (verbatim r14/r17 body). 1-D grid with
// b = blockIdx&7 so each XCD pools ONE batch: window float4 loads hit L2.
__global__ __launch_bounds__(256) void k_pool(const float* __restrict__ fr,
                                              const float* __restrict__ bcg,
                                              const float* __restrict__ numfrg,
                                              const int* __restrict__ lotbl,
                                              float* __restrict__ out){
  int tid = threadIdx.x;
  int lane = tid & 63, w = tid >> 6;
  int b = blockIdx.x & 7;
  int sblk = blockIdx.x >> 3;                 // 0..511
  int s = sblk * 4 + w;
  float numfr = numfrg[b];
  float4 acc = {0.0f, 0.0f, 0.0f, 0.0f};
  if ((float)(sblk * 4 + 1) <= numfr && (float)(s + 1) <= numfr){
    float cc = (float)(s + 1);
    float hiv = cc + 1.0f;
    int lo = lotbl[b * S_ + s];
    const float* bcb = bcg + b * T_;
    const float4* f4 = (const float4*)(fr + (size_t)b * T_ * D_);
    float scol = 0.0f;
    for (int base = lo; base < T_; base += 64){
      int t = base + lane;
      float bcv = (t < T_) ? bcb[t] : 1e30f;
      bool in = bcv <= hiv;
      float r = in ? 1.0f - tanhf(10.0f * fabsf(cc - bcv)) : 0.0f;
      #pragma unroll
      for (int m = 32; m >= 1; m >>= 1) r += __shfl_xor(r, m, 64);
      scol += r;
      if (__popcll(__ballot(in)) < 64) break;
    }
    for (int base = lo; base < T_; base += 64){
      int t = base + lane;
      float bcv = (t < T_) ? bcb[t] : 1e30f;
      bool in = bcv <= hiv;
      float mval = 0.0f;
      if (in){
        float u = tanhf(10.0f * fabsf(cc - bcv));
        mval = (1.0f - u) / (scol + u);
      }
      int cnt = __popcll(__ballot(in));
      for (int j = 0; j < cnt; ++j){
        float mj = __shfl(mval, j, 64);
        float4 f = f4[(size_t)(base + j) * 64 + lane];
        acc.x += mj * f.x; acc.y += mj * f.y; acc.z += mj * f.z; acc.w += mj * f.w;
      }
      if (cnt < 64) break;
    }
  }
  ((float4*)out)[((size_t)b * S_ + s) * 64 + lane] = acc;
}

extern "C" void kernel_launch(void* const* d_in, const int* in_sizes, int n_in,
                              void* d_out, int out_size, void* d_ws, size_t ws_size,
                              hipStream_t stream) {
  const float* frames = (const float*)d_in[0];
  float* ws = (float*)d_ws;
  float* cosg   = ws;                    // B*T
  float* bcg    = ws + B_ * T_;          // B*T
  float* numfrg = ws + 2 * B_ * T_;      // B
  int*   lotbl  = (int*)(ws + 2 * B_ * T_ + 64);   // B*S ints
  float* out = (float*)d_out;

  k_dotcos<<<B_ * T_ / 4, 256, 0, stream>>>(frames, cosg);
  k_boundary<<<B_, 256, 0, stream>>>(cosg, bcg, numfrg, lotbl);
  k_pool<<<B_ * S_ / 4, 256, 0, stream>>>(frames, bcg, numfrg, lotbl, out);
}

// Round 19
// 23.121 us; speedup vs baseline: 19.2903x; 1.0151x over previous
//
#include <hip/hip_runtime.h>
#include <hip/hip_bf16.h>

#define B_ 8
#define T_ 2048
#define D_ 256
#define S_ 2048

// Kernel 1: cos[b,t] = <f[t],f[t+1]> / max(|f[t]||f[t+1]|, 1e-6), t in [0,T-2].
// One wave per row t. 1-D grid with b = blockIdx&7: under the g%8 XCD
// round-robin each XCD serves ONE batch (2.1MB frames -> L2-resident).
__global__ __launch_bounds__(256) void k_dotcos(const float* __restrict__ fr,
                                                float* __restrict__ cosg){
  int lane = threadIdx.x & 63;
  int w = threadIdx.x >> 6;
  int b = blockIdx.x & 7;
  int chunk = blockIdx.x >> 3;                // 0..511
  int t = chunk * 4 + w;                      // 0..2047
  int p = b * T_ + t;
  const float4* f4 = (const float4*)fr;
  float4 a = f4[(size_t)p * 64 + lane];
  float na = a.x*a.x + a.y*a.y + a.z*a.z + a.w*a.w;
  float nc = 0.0f, dt = 0.0f;
  if (t < T_ - 1){
    float4 c = f4[(size_t)(p + 1) * 64 + lane];
    nc = c.x*c.x + c.y*c.y + c.z*c.z + c.w*c.w;
    dt = a.x*c.x + a.y*c.y + a.z*c.z + a.w*c.w;
  }
  #pragma unroll
  for (int m = 32; m >= 1; m >>= 1){
    na += __shfl_xor(na, m, 64);
    nc += __shfl_xor(nc, m, 64);
    dt += __shfl_xor(dt, m, 64);
  }
  if (lane == 0 && t < T_ - 1)
    cosg[p] = dt / fmaxf(sqrtf(na) * sqrtf(nc), 1e-6f);
}

// Kernel 2: per batch: minmax(cos) -> d -> p2 -> b -> block scan -> bc,
// lotbl via event scatter (verbatim r18, proven absmax 0.0).
__global__ __launch_bounds__(256) void k_boundary(const float* __restrict__ cosg,
                                                  float* __restrict__ bcg,
                                                  float* __restrict__ numfrg,
                                                  int* __restrict__ lotbl){
  __shared__ float sd[T_];
  __shared__ float sb[T_];
  __shared__ float smin[4], smax[4], swv[4];
  int b = blockIdx.x, tid = threadIdx.x;
  int lane = tid & 63, w = tid >> 6;
  const float* cG = cosg + b * T_;
  for (int t = tid; t < T_ - 1; t += 256) sd[t] = cG[t];
  for (int si = tid; si < S_; si += 256) lotbl[b * S_ + si] = 0;
  __syncthreads();
  float mn = 1e30f, mx = -1e30f;
  for (int t = tid; t < T_ - 1; t += 256){ float v = sd[t]; mn = fminf(mn, v); mx = fmaxf(mx, v); }
  #pragma unroll
  for (int m = 32; m >= 1; m >>= 1){
    mn = fminf(mn, __shfl_xor(mn, m, 64));
    mx = fmaxf(mx, __shfl_xor(mx, m, 64));
  }
  if (lane == 0){ smin[w] = mn; smax[w] = mx; }
  __syncthreads();
  mn = fminf(fminf(smin[0], smin[1]), fminf(smin[2], smin[3]));
  mx = fmaxf(fmaxf(smax[0], smax[1]), fmaxf(smax[2], smax[3]));
  float inv = 1.0f / (mx - mn);
  for (int t = tid; t < T_ - 1; t += 256)
    sd[t] = 1.0f - (sd[t] - mn) * inv;
  __syncthreads();
  for (int t = tid; t < T_; t += 256){
    float v;
    if (t == 0) v = 1.0f;
    else {
      int i = t - 1;                          // index into d (length T-1)
      if (i < 2 || i > T_ - 4) v = 0.0f;      // p2[:, :2] = 0, p2[:, -2:] = 0
      else {
        float d0 = sd[i];
        float p2 = fminf(fmaxf(d0 - sd[i + 2], 0.0f), fmaxf(d0 - sd[i - 2], 0.0f));
        v = tanhf(1e7f * p2);
      }
    }
    sb[t] = v;
  }
  __syncthreads();
  float loc[8]; float s = 0.0f;
  #pragma unroll
  for (int j = 0; j < 8; ++j){ s += sb[8 * tid + j]; loc[j] = s; }
  float v = s;
  #pragma unroll
  for (int off = 1; off < 64; off <<= 1){
    float n = __shfl_up(v, (unsigned)off, 64);
    if (lane >= off) v += n;
  }
  if (lane == 63) swv[w] = v;
  __syncthreads();
  float wpre = 0.0f;
  for (int i = 0; i < w; ++i) wpre += swv[i];
  float excl = wpre + v - s;
  #pragma unroll
  for (int j = 0; j < 8; ++j) bcg[b * T_ + 8 * tid + j] = excl + loc[j];
  if (tid == 255) numfrg[b] = excl + s;
  __threadfence_block();
  __syncthreads();
  #pragma unroll
  for (int j = 0; j < 8; ++j){
    if (sb[8 * tid + j] == 1.0f){
      int k = (int)(excl + loc[j]);           // bc[t], an exact integer
      if (k < S_) lotbl[b * S_ + k] = 8 * tid + j;
    }
  }
}

// Kernel 3: one WAVE per s. SINGLE-PASS fast path: window fits one 64-lane
// tile (always, in practice) -> u/res computed once, scol via wave reduce,
// mval from regs, fma sweep. Bit-identical values/order vs the two-pass r18
// body; if the window spills (cnt==64), fall back to verbatim r18 two-pass.
__global__ __launch_bounds__(256) void k_pool(const float* __restrict__ fr,
                                              const float* __restrict__ bcg,
                                              const float* __restrict__ numfrg,
                                              const int* __restrict__ lotbl,
                                              float* __restrict__ out){
  int tid = threadIdx.x;
  int lane = tid & 63, w = tid >> 6;
  int b = blockIdx.x & 7;
  int sblk = blockIdx.x >> 3;                 // 0..511
  int s = sblk * 4 + w;
  float numfr = numfrg[b];
  float4 acc = {0.0f, 0.0f, 0.0f, 0.0f};
  if ((float)(sblk * 4 + 1) <= numfr && (float)(s + 1) <= numfr){
    float cc = (float)(s + 1);
    float hiv = cc + 1.0f;
    int lo = lotbl[b * S_ + s];
    const float* bcb = bcg + b * T_;
    const float4* f4 = (const float4*)(fr + (size_t)b * T_ * D_);
    // fast path: one tile
    int t0 = lo + lane;
    float bcv0 = (t0 < T_) ? bcb[t0] : 1e30f;
    bool in0 = bcv0 <= hiv;
    unsigned long long blt = __ballot(in0);
    int cnt = __popcll(blt);
    if (cnt < 64){
      float u0 = in0 ? tanhf(10.0f * fabsf(cc - bcv0)) : 0.0f;
      float r = in0 ? 1.0f - u0 : 0.0f;
      #pragma unroll
      for (int m = 32; m >= 1; m >>= 1) r += __shfl_xor(r, m, 64);
      float scol = r;
      float mval = in0 ? (1.0f - u0) / (scol + u0) : 0.0f;
      for (int j = 0; j < cnt; ++j){
        float mj = __shfl(mval, j, 64);
        float4 f = f4[(size_t)(lo + j) * 64 + lane];
        acc.x += mj * f.x; acc.y += mj * f.y; acc.z += mj * f.z; acc.w += mj * f.w;
      }
    } else {
      // fallback: verbatim r18 two-pass (window > 64; pathological)
      float scol = 0.0f;
      for (int base = lo; base < T_; base += 64){
        int t = base + lane;
        float bcv = (t < T_) ? bcb[t] : 1e30f;
        bool in = bcv <= hiv;
        float r = in ? 1.0f - tanhf(10.0f * fabsf(cc - bcv)) : 0.0f;
        #pragma unroll
        for (int m = 32; m >= 1; m >>= 1) r += __shfl_xor(r, m, 64);
        scol += r;
        if (__popcll(__ballot(in)) < 64) break;
      }
      for (int base = lo; base < T_; base += 64){
        int t = base + lane;
        float bcv = (t < T_) ? bcb[t] : 1e30f;
        bool in = bcv <= hiv;
        float mval = 0.0f;
        if (in){
          float u = tanhf(10.0f * fabsf(cc - bcv));
          mval = (1.0f - u) / (scol + u);
        }
        int c2 = __popcll(__ballot(in));
        for (int j = 0; j < c2; ++j){
          float mj = __shfl(mval, j, 64);
          float4 f = f4[(size_t)(base + j) * 64 + lane];
          acc.x += mj * f.x; acc.y += mj * f.y; acc.z += mj * f.z; acc.w += mj * f.w;
        }
        if (c2 < 64) break;
      }
    }
  }
  ((float4*)out)[((size_t)b * S_ + s) * 64 + lane] = acc;
}

extern "C" void kernel_launch(void* const* d_in, const int* in_sizes, int n_in,
                              void* d_out, int out_size, void* d_ws, size_t ws_size,
                              hipStream_t stream) {
  const float* frames = (const float*)d_in[0];
  float* ws = (float*)d_ws;
  float* cosg   = ws;                    // B*T
  float* bcg    = ws + B_ * T_;          // B*T
  float* numfrg = ws + 2 * B_ * T_;      // B
  int*   lotbl  = (int*)(ws + 2 * B_ * T_ + 64);   // B*S ints
  float* out = (float*)d_out;

  k_dotcos<<<B_ * T_ / 4, 256, 0, stream>>>(frames, cosg);
  k_boundary<<<B_, 256, 0, stream>>>(cosg, bcg, numfrg, lotbl);
  k_pool<<<B_ * S_ / 4, 256, 0, stream>>>(frames, bcg, numfrg, lotbl, out);
}